// Round 1
// baseline (328.312 us; speedup 1.0000x reference)
//
#include <hip/hip_runtime.h>

// Problem constants
#define B_    512
#define N_    64
#define FIN_  128
#define H_    256
#define K_    32
#define S_    4
#define SB_   2048

static constexpr float TINYF = 1.17549435e-38f;

// ---------------------------------------------------------------------------
// Threefry-2x32, key = (0, 42) (jax.random.key(42)), partitionable path:
// per flat index i: cipher (hi=0, lo=i), bits = y0 ^ y1.
// ---------------------------------------------------------------------------
__device__ __forceinline__ unsigned tf_bits(unsigned lo) {
  const unsigned ks0 = 0u, ks1 = 42u, ks2 = 0x1BD11BF0u;  // 0 ^ 42 ^ 0x1BD11BDA
  unsigned x0 = 0u + ks0;
  unsigned x1 = lo + ks1;
#define TFR(r) { x0 += x1; x1 = (x1 << r) | (x1 >> (32 - r)); x1 ^= x0; }
  TFR(13) TFR(15) TFR(26) TFR(6)
  x0 += ks1; x1 += ks2 + 1u;
  TFR(17) TFR(29) TFR(16) TFR(24)
  x0 += ks2; x1 += ks0 + 2u;
  TFR(13) TFR(15) TFR(26) TFR(6)
  x0 += ks0; x1 += ks1 + 3u;
  TFR(17) TFR(29) TFR(16) TFR(24)
  x0 += ks1; x1 += ks2 + 4u;
  TFR(13) TFR(15) TFR(26) TFR(6)
  x0 += ks2; x1 += ks0 + 5u;
#undef TFR
  return x0 ^ x1;
}

// ---------------------------------------------------------------------------
// Mask dtype auto-detect: flag 0 = int32 {0,1}, 1 = float32 {0,1.0f}, 2 = byte
// Scans only first 8192 words (32 KB) -> safe under every encoding.
// ---------------------------------------------------------------------------
__global__ void k_detect(const unsigned* __restrict__ w, int* __restrict__ flag) {
  __shared__ int s_notint, s_notflt;
  if (threadIdx.x == 0) { s_notint = 0; s_notflt = 0; }
  __syncthreads();
  int ni = 0, nf = 0;
  for (int i = threadIdx.x; i < 8192; i += 256) {
    unsigned v = w[i];
    if (v > 1u) ni = 1;
    if (v != 0u && v != 0x3f800000u) nf = 1;
  }
  if (ni) atomicOr(&s_notint, 1);
  if (nf) atomicOr(&s_notflt, 1);
  __syncthreads();
  if (threadIdx.x == 0) *flag = s_notint ? (s_notflt ? 2 : 1) : 0;
}

__global__ void k_mask(const void* __restrict__ mptr, const int* __restrict__ flag,
                       float* __restrict__ maskf) {
  int i = blockIdx.x * 256 + threadIdx.x;
  if (i >= B_ * N_) return;
  int fl = *flag;
  float r;
  if (fl == 0)      r = ((const int*)mptr)[i] ? 1.0f : 0.0f;
  else if (fl == 1) r = (((const float*)mptr)[i] != 0.0f) ? 1.0f : 0.0f;
  else              r = ((const unsigned char*)mptr)[i] ? 1.0f : 0.0f;
  maskf[i] = r;
}

// ---------------------------------------------------------------------------
// Per-batch prep: normalized adjacency Ahat = D^-1/2 (A+I) D^-1/2, and
// neighbor bitmasks (adj>0) per node. adj is symmetric.
// ---------------------------------------------------------------------------
__global__ __launch_bounds__(256) void k_prep(const float* __restrict__ adj,
                                              float* __restrict__ Ahat,
                                              unsigned long long* __restrict__ nbr) {
  __shared__ float adjS[4096];
  __shared__ float dis[64];
  int b = blockIdx.x, tid = threadIdx.x;
  const float* ab = adj + (size_t)b * 4096;
  for (int i = tid; i < 4096; i += 256) adjS[i] = ab[i];
  __syncthreads();
  if (tid < 64) {
    float s = 0.0f;
    unsigned long long m = 0ull;
    for (int j = 0; j < 64; ++j) {
      float v = adjS[j * 64 + tid];            // == adj[tid][j] (symmetric), coalesced banks
      s += (j == tid) ? (v + 1.0f) : v;        // A = adj + I, reference sum order
      if (v != 0.0f) m |= (1ull << j);
    }
    dis[tid] = 1.0f / sqrtf(fmaxf(s, 1.0f));
    nbr[b * 64 + tid] = m;
  }
  __syncthreads();
  float* Ab = Ahat + (size_t)b * 4096;
  for (int i = tid; i < 4096; i += 256) {
    int r = i >> 6, c = i & 63;
    float a = adjS[i] + ((r == c) ? 1.0f : 0.0f);
    Ab[i] = (dis[r] * a) * dis[c];
  }
}

// ---------------------------------------------------------------------------
// fp32 GEMM C[M,256] = A[M,K] @ Bm[K,256], 64x64 tile, BK=16, 4x4 per thread.
// ---------------------------------------------------------------------------
__global__ __launch_bounds__(256) void k_gemm64(const float* __restrict__ A,
                                                const float* __restrict__ Bm,
                                                float* __restrict__ C, int K) {
  __shared__ float As[16][64];
  __shared__ float Bs[16][68];
  int bm = blockIdx.x * 64, bn = blockIdx.y * 64;
  int tid = threadIdx.x;
  int tx = tid & 15, ty = tid >> 4;
  int ar = tid >> 2, ac = (tid & 3) * 4;
  int br = tid >> 4, bc = (tid & 15) * 4;
  float acc[4][4] = {};
  for (int k0 = 0; k0 < K; k0 += 16) {
    float4 av = *(const float4*)&A[(size_t)(bm + ar) * K + k0 + ac];
    float4 bv = *(const float4*)&Bm[(size_t)(k0 + br) * H_ + bn + bc];
    As[ac + 0][ar] = av.x; As[ac + 1][ar] = av.y;
    As[ac + 2][ar] = av.z; As[ac + 3][ar] = av.w;
    *(float4*)&Bs[br][bc] = bv;
    __syncthreads();
#pragma unroll
    for (int kk = 0; kk < 16; ++kk) {
      float a4[4], b4[4];
      *(float4*)a4 = *(const float4*)&As[kk][ty * 4];
      *(float4*)b4 = *(const float4*)&Bs[kk][tx * 4];
#pragma unroll
      for (int i = 0; i < 4; ++i)
#pragma unroll
        for (int j = 0; j < 4; ++j) acc[i][j] += a4[i] * b4[j];
    }
    __syncthreads();
  }
#pragma unroll
  for (int i = 0; i < 4; ++i) {
    float4 v = make_float4(acc[i][0], acc[i][1], acc[i][2], acc[i][3]);
    *(float4*)&C[(size_t)(bm + ty * 4 + i) * H_ + bn + tx * 4] = v;
  }
}

// ---------------------------------------------------------------------------
// out[b,i,f] = relu( maskf[b,i] * (sum_j Ahat[b,i,j] * T[b,j,f] + bias[f]) )
// ---------------------------------------------------------------------------
__global__ __launch_bounds__(256) void k_agg(const float* __restrict__ Ahat,
                                             const float* __restrict__ T,
                                             const float* __restrict__ bias,
                                             const float* __restrict__ maskf,
                                             float* __restrict__ out) {
  __shared__ float Ts[64 * 256];   // 64 KB
  int b = blockIdx.x, f = threadIdx.x;
  const float* Tb = T + (size_t)b * 16384;
  for (int i = f; i < 16384; i += 256) Ts[i] = Tb[i];
  __syncthreads();
  const float* Ab = Ahat + (size_t)b * 4096;
  const float* mb = maskf + b * 64;
  float bv = bias[f];
  for (int i0 = 0; i0 < 64; i0 += 8) {
    float acc[8] = {0, 0, 0, 0, 0, 0, 0, 0};
    for (int j = 0; j < 64; ++j) {
      float tv = Ts[j * 256 + f];
#pragma unroll
      for (int u = 0; u < 8; ++u) acc[u] += Ab[(i0 + u) * 64 + j] * tv;  // uniform -> s_load
    }
#pragma unroll
    for (int u = 0; u < 8; ++u) {
      int i = i0 + u;
      out[((size_t)b * 64 + i) * 256 + f] = fmaxf((acc[u] + bv) * mb[i], 0.0f);
    }
  }
}

// ---------------------------------------------------------------------------
// Per (b,n): cdist to 32 centroids, softmin(T=0.1), Gumbel-max sample s=0..3.
// ---------------------------------------------------------------------------
__global__ __launch_bounds__(256) void k_cdist_sample(const float* __restrict__ h,
                                                      const float* __restrict__ cen,
                                                      int* __restrict__ conc,
                                                      float* __restrict__ pp) {
  int bn = blockIdx.x, tid = threadIdx.x;
  __shared__ float hs[256];
  __shared__ float red[4];
  __shared__ float dls[32];
  __shared__ float psh[32];
  float hv = h[(size_t)bn * 256 + tid];
  hs[tid] = hv;
  float s = hv * hv;
#pragma unroll
  for (int d = 1; d < 64; d <<= 1) s += __shfl_xor(s, d, 64);
  if ((tid & 63) == 0) red[tid >> 6] = s;
  __syncthreads();
  float hh = (red[0] + red[1]) + (red[2] + red[3]);
  int k = tid >> 3, l8 = tid & 7;
  const float* ck = cen + k * 256;
  float dacc = 0.0f, cacc = 0.0f;
#pragma unroll 8
  for (int m = 0; m < 32; ++m) {
    float cv = ck[l8 + 8 * m];
    dacc += hs[l8 + 8 * m] * cv;
    cacc += cv * cv;
  }
#pragma unroll
  for (int d = 1; d < 8; d <<= 1) {
    dacc += __shfl_xor(dacc, d, 64);
    cacc += __shfl_xor(cacc, d, 64);
  }
  if (l8 == 0) {
    float d2 = (hh + cacc) - 2.0f * dacc;       // reference expansion order
    float dist = sqrtf(fmaxf(d2, 1e-12f));
    dls[k] = -dist / 0.1f;
  }
  __syncthreads();
  if (tid < 32) {
    float l = dls[tid];
    float mx = l;
#pragma unroll
    for (int d = 1; d < 32; d <<= 1) mx = fmaxf(mx, __shfl_xor(mx, d, 32));
    float sh = l - mx;
    float e = expf(sh);
    float den = e;
#pragma unroll
    for (int d = 1; d < 32; d <<= 1) den += __shfl_xor(den, d, 32);
    float p = e / den;
    float lp = sh - logf(den);
    psh[tid] = p;
#pragma unroll
    for (int s4 = 0; s4 < 4; ++s4) {
      unsigned flat = (unsigned)(s4 * 32768 + bn) * 32u + (unsigned)tid;
      unsigned bits = tf_bits(flat);
      float fu = __uint_as_float((bits >> 9) | 0x3f800000u) - 1.0f;
      float u = fmaxf(TINYF, fu * (1.0f - TINYF) + TINYF);   // jax uniform(tiny,1)
      float g = -logf(-logf(u));
      float v = lp + g;
      int bi = tid;
#pragma unroll
      for (int d = 1; d < 32; d <<= 1) {        // max with first-index ties
        float ov = __shfl_xor(v, d, 32);
        int oi = __shfl_xor(bi, d, 32);
        if (ov > v || (ov == v && oi < bi)) { v = ov; bi = oi; }
      }
      if (tid == 0) {
        conc[s4 * 32768 + bn] = bi;
        pp[s4 * 32768 + bn] = psh[bi];
      }
    }
  }
}

// ---------------------------------------------------------------------------
// Per (s,b): same-concept CC (Jacobi min-label fixpoint), graph_prob, labels,
// cluster bitmasks. One wave per block.
// ---------------------------------------------------------------------------
__global__ __launch_bounds__(64) void k_percc(const int* __restrict__ conc,
                                              const float* __restrict__ pp,
                                              const float* __restrict__ maskf,
                                              const unsigned long long* __restrict__ nbr,
                                              int* __restrict__ labels,
                                              unsigned long long* __restrict__ clmask,
                                              float* __restrict__ out_gp,
                                              float* __restrict__ out_lab) {
  int sb = blockIdx.x, b = sb & 511, lane = threadIdx.x;
  __shared__ int cs[64];
  __shared__ int lab[64];
  __shared__ int labf[64];
  __shared__ int chg;
  int c = conc[sb * 64 + lane];
  cs[lane] = c;
  bool mk = maskf[b * 64 + lane] != 0.0f;
  unsigned long long nb = nbr[b * 64 + lane];
  __syncthreads();
  unsigned long long sm = 0ull;
  for (int j = 0; j < 64; ++j)
    if (((nb >> j) & 1ull) && cs[j] == c) sm |= (1ull << j);
  lab[lane] = lane + 1;
  __syncthreads();
  for (int it = 0; it < 64; ++it) {
    if (lane == 0) chg = 0;
    int m = lab[lane];
    unsigned long long t = sm;
    while (t) { int j = __ffsll((unsigned long long)t) - 1; m = min(m, lab[j]); t &= t - 1; }
    __syncthreads();
    if (m < lab[lane]) { lab[lane] = m; chg = 1; }
    __syncthreads();
    if (chg == 0) break;
  }
  int lf = mk ? lab[lane] : 0;
  labels[sb * 64 + lane] = lf;
  out_lab[sb * 64 + lane] = (float)lf;
  float pv = mk ? pp[sb * 64 + lane] : 1.0f;
#pragma unroll
  for (int d = 1; d < 64; d <<= 1) pv *= __shfl_xor(pv, d, 64);
  if (lane == 0) out_gp[sb] = pv;
  labf[lane] = lf;
  __syncthreads();
  unsigned long long cm = 0ull;
  for (int j = 0; j < 64; ++j)
    if (labf[j] == lane + 1) cm |= (1ull << j);
  clmask[sb * 64 + lane] = cm;
}

// ---------------------------------------------------------------------------
// new_x[sb,c,:] = mean of h[b,j,:] over cluster-(c+1) nodes (0 if empty).
// ---------------------------------------------------------------------------
__global__ __launch_bounds__(256) void k_newx(const float* __restrict__ h,
                                              const unsigned long long* __restrict__ clmask,
                                              float* __restrict__ out_newx) {
  int sb = blockIdx.x, b = sb & 511, f = threadIdx.x;
  const float* hb = h + (size_t)b * 16384;
  for (int c = 0; c < 64; ++c) {
    unsigned long long m = clmask[sb * 64 + c];   // uniform -> scalar load
    int cnt = __popcll(m);
    float acc = 0.0f;
    unsigned long long t = m;
    while (t) { int j = __ffsll((unsigned long long)t) - 1; acc += hb[j * 256 + f]; t &= t - 1; }
    out_newx[((size_t)sb * 64 + c) * 256 + f] = acc / (float)(cnt > 0 ? cnt : 1);
  }
}

// ---------------------------------------------------------------------------
// new_adj[sb,c,d] = 1 iff exists edge (i,j), labels i->c+1, j->d+1.
// ---------------------------------------------------------------------------
__global__ __launch_bounds__(256) void k_newadj(const int* __restrict__ labels,
                                                const unsigned long long* __restrict__ nbr,
                                                float* __restrict__ out_newadj) {
  __shared__ float o[4096];
  __shared__ int lab[64];
  __shared__ unsigned long long nbs[64];
  int sb = blockIdx.x, b = sb & 511, tid = threadIdx.x;
  for (int i = tid; i < 4096; i += 256) o[i] = 0.0f;
  if (tid < 64) { lab[tid] = labels[sb * 64 + tid]; nbs[tid] = nbr[b * 64 + tid]; }
  __syncthreads();
  for (int p = tid; p < 4096; p += 256) {
    int i = p >> 6, j = p & 63;
    int li = lab[i], lj = lab[j];
    if (li > 0 && lj > 0 && ((nbs[i] >> j) & 1ull))
      o[(li - 1) * 64 + (lj - 1)] = 1.0f;       // benign same-value races
  }
  __syncthreads();
  for (int i = tid; i < 4096; i += 256) out_newadj[(size_t)sb * 4096 + i] = o[i];
}

// ---------------------------------------------------------------------------
extern "C" void kernel_launch(void* const* d_in, const int* in_sizes, int n_in,
                              void* d_out, int out_size, void* d_ws, size_t ws_size,
                              hipStream_t stream) {
  (void)in_sizes; (void)n_in; (void)out_size; (void)ws_size;
  const float* x   = (const float*)d_in[0];
  const float* adj = (const float*)d_in[1];
  const void*  mp  = d_in[2];
  const float* W1  = (const float*)d_in[3];
  const float* b1  = (const float*)d_in[4];
  const float* W2  = (const float*)d_in[5];
  const float* b2  = (const float*)d_in[6];
  const float* cen = (const float*)d_in[7];

  char* ws = (char*)d_ws;
  float* Ahat = (float*)ws;                                            // 8 MB
  float* bufA = (float*)(ws + (size_t)(8u  << 20));                    // 32 MB (XW / HW)
  float* bufB = (float*)(ws + (size_t)(40u << 20));                    // 32 MB (h1 / h)
  unsigned long long* nbr = (unsigned long long*)(ws + (size_t)(72u << 20));       // 256 KB
  float* maskf = (float*)(ws + (size_t)(72u << 20) + (256u  << 10));   // 128 KB
  int*   conc  = (int*)  (ws + (size_t)(72u << 20) + (384u  << 10));   // 512 KB
  float* pp    = (float*)(ws + (size_t)(72u << 20) + (896u  << 10));   // 512 KB
  int*   labels= (int*)  (ws + (size_t)(72u << 20) + (1408u << 10));   // 512 KB
  unsigned long long* clmask = (unsigned long long*)(ws + (size_t)(72u << 20) + (1920u << 10)); // 1 MB
  int*   flag  = (int*)  (ws + (size_t)(72u << 20) + (2944u << 10));

  float* out        = (float*)d_out;
  float* out_newx   = out;                 // 2048*64*256
  float* out_newadj = out + 33554432;      // 2048*64*64
  float* out_gp     = out + 41943040;      // 2048
  float* out_lab    = out + 41945088;      // 2048*64

  hipLaunchKernelGGL(k_detect, dim3(1), dim3(256), 0, stream, (const unsigned*)mp, flag);
  hipLaunchKernelGGL(k_mask,   dim3(128), dim3(256), 0, stream, mp, flag, maskf);
  hipLaunchKernelGGL(k_prep,   dim3(512), dim3(256), 0, stream, adj, Ahat, nbr);
  hipLaunchKernelGGL(k_gemm64, dim3(512, 4), dim3(256), 0, stream, x, W1, bufA, 128);
  hipLaunchKernelGGL(k_agg,    dim3(512), dim3(256), 0, stream, Ahat, bufA, b1, maskf, bufB);
  hipLaunchKernelGGL(k_gemm64, dim3(512, 4), dim3(256), 0, stream, bufB, W2, bufA, 256);
  hipLaunchKernelGGL(k_agg,    dim3(512), dim3(256), 0, stream, Ahat, bufA, b2, maskf, bufB);
  hipLaunchKernelGGL(k_cdist_sample, dim3(32768), dim3(256), 0, stream, bufB, cen, conc, pp);
  hipLaunchKernelGGL(k_percc,  dim3(2048), dim3(64), 0, stream, conc, pp, maskf, nbr,
                     labels, clmask, out_gp, out_lab);
  hipLaunchKernelGGL(k_newx,   dim3(2048), dim3(256), 0, stream, bufB, clmask, out_newx);
  hipLaunchKernelGGL(k_newadj, dim3(2048), dim3(256), 0, stream, labels, nbr, out_newadj);
}